// Round 10
// baseline (697.836 us; speedup 1.0000x reference)
//
#include <hip/hip_runtime.h>

#define N_NODES 20000
#define N_EDGES 320000
#define N_REL   100
#define FDIM    256
#define NHEAD   8
#define HDIM    32
#define SCAN_BLOCKS ((N_NODES + 255) / 256)   // 79

using short8 = __attribute__((ext_vector_type(8))) short;   // 8 bf16 in 4 VGPRs
using f32x4  = __attribute__((ext_vector_type(4))) float;

__device__ inline unsigned short f2bf(float f) {
    union { float f; unsigned int u; } v; v.f = f;
    unsigned int r = v.u + 0x7fff + ((v.u >> 16) & 1);   // RNE
    return (unsigned short)(r >> 16);
}
__device__ inline float bf2f(unsigned short u) {
    union { unsigned int i; float f; } v; v.i = ((unsigned int)u) << 16; return v.f;
}
__device__ inline float4 bf4(ushort4 u) {
    return make_float4(bf2f(u.x), bf2f(u.y), bf2f(u.z), bf2f(u.w));
}
// unpack 8 bf16 (uint4) -> 8 fp32
__device__ inline void unpack8(float* d, uint4 u) {
    union { unsigned int u; float f; } t;
    t.u = u.x << 16;         d[0] = t.f;
    t.u = u.x & 0xffff0000u; d[1] = t.f;
    t.u = u.y << 16;         d[2] = t.f;
    t.u = u.y & 0xffff0000u; d[3] = t.f;
    t.u = u.z << 16;         d[4] = t.f;
    t.u = u.z & 0xffff0000u; d[5] = t.f;
    t.u = u.w << 16;         d[6] = t.f;
    t.u = u.w & 0xffff0000u; d[7] = t.f;
}

// ---------------------------------------------------------------------------
// LayerNorm over 256 features -> bf16 output. One wave per row.
// ---------------------------------------------------------------------------
__global__ __launch_bounds__(64) void ln_bf16_kernel(
    const float* __restrict__ in, const float* __restrict__ g,
    const float* __restrict__ b, unsigned short* __restrict__ out, int rows)
{
    int row = blockIdx.x;
    if (row >= rows) return;
    int tid = threadIdx.x;
    const float4 v = *(const float4*)(in + (size_t)row * FDIM + tid * 4);
    float s = v.x + v.y + v.z + v.w;
    float q = v.x * v.x + v.y * v.y + v.z * v.z + v.w * v.w;
    #pragma unroll
    for (int d = 1; d < 64; d <<= 1) { s += __shfl_xor(s, d); q += __shfl_xor(q, d); }
    float mean = s * (1.0f / FDIM);
    float var  = q * (1.0f / FDIM) - mean * mean;
    float inv  = rsqrtf(var + 1e-5f);
    float4 gg = *(const float4*)(g + tid * 4);
    float4 bb = *(const float4*)(b + tid * 4);
    ushort4 o;
    o.x = f2bf((v.x - mean) * inv * gg.x + bb.x);
    o.y = f2bf((v.y - mean) * inv * gg.y + bb.y);
    o.z = f2bf((v.z - mean) * inv * gg.z + bb.z);
    o.w = f2bf((v.w - mean) * inv * gg.w + bb.w);
    *(ushort4*)(out + (size_t)row * FDIM + tid * 4) = o;
}

// rst = bf2f(featH) + ent (fp32) ; y = LN(rst) (bf16). featH is head-major [8][N][32].
__global__ __launch_bounds__(64) void rst_ln_kernel(
    const unsigned short* __restrict__ featH, const float* __restrict__ ent,
    const float* __restrict__ g, const float* __restrict__ b,
    float* __restrict__ rst, unsigned short* __restrict__ y)
{
    int row = blockIdx.x;
    int tid = threadIdx.x;
    int h = tid >> 3;                      // head of dims tid*4..tid*4+3
    const ushort4 fu = *(const ushort4*)(featH + ((size_t)h * N_NODES + row) * 32 + (tid & 7) * 4);
    const float4 f = bf4(fu);
    const float4 e = *(const float4*)(ent + (size_t)row * FDIM + tid * 4);
    float4 r;
    r.x = f.x + e.x; r.y = f.y + e.y; r.z = f.z + e.z; r.w = f.w + e.w;
    *(float4*)(rst + (size_t)row * FDIM + tid * 4) = r;
    float s = r.x + r.y + r.z + r.w;
    float q = r.x * r.x + r.y * r.y + r.z * r.z + r.w * r.w;
    #pragma unroll
    for (int d = 1; d < 64; d <<= 1) { s += __shfl_xor(s, d); q += __shfl_xor(q, d); }
    float mean = s * (1.0f / FDIM);
    float var  = q * (1.0f / FDIM) - mean * mean;
    float inv  = rsqrtf(var + 1e-5f);
    float4 gg = *(const float4*)(g + tid * 4);
    float4 bb = *(const float4*)(b + tid * 4);
    ushort4 o;
    o.x = f2bf((r.x - mean) * inv * gg.x + bb.x);
    o.y = f2bf((r.y - mean) * inv * gg.y + bb.y);
    o.z = f2bf((r.z - mean) * inv * gg.z + bb.z);
    o.w = f2bf((r.w - mean) * inv * gg.w + bb.w);
    *(ushort4*)(y + (size_t)row * FDIM + tid * 4) = o;
}

// Wt[n*K + k] = bf16(W[k*N + n])
__global__ void transpose_bf16_kernel(const float* __restrict__ W,
                                      unsigned short* __restrict__ Wt, int K, int N)
{
    int idx = blockIdx.x * 256 + threadIdx.x;
    if (idx >= K * N) return;
    int n = idx / K, k = idx - n * K;
    Wt[idx] = f2bf(W[(size_t)k * N + n]);
}

// repack fen (projb cols 512..767, row-major) -> F0 head-major [8][N][32], dword granularity
__global__ void repack_fen_kernel(const unsigned short* __restrict__ projb,
                                  unsigned short* __restrict__ F0, int n)
{
    int idx = blockIdx.x * 256 + threadIdx.x;
    int total = n * 128;                 // dwords
    if (idx >= total) return;
    int row = idx >> 7, d2 = idx & 127;  // d2: dword in row (2 dims)
    int h = d2 >> 4, w = d2 & 15;
    ((unsigned int*)F0)[((size_t)h * n + row) * 16 + w] =
        ((const unsigned int*)projb)[(size_t)row * 384 + 256 + d2];
}

// ---------------------------------------------------------------------------
// bf16 MFMA GEMM (B^T): 128x128 tile, 4 waves, 4x4 frags, BK=32.
// ---------------------------------------------------------------------------
__global__ __launch_bounds__(256) void mfma_gemm_bt(
    const unsigned short* __restrict__ A, const unsigned short* __restrict__ Bt,
    const float* __restrict__ bias, const float* __restrict__ add,
    float* __restrict__ Cf, unsigned short* __restrict__ Cb,
    int M, int K, int N, int relu)
{
    __shared__ unsigned short As[128 * 32];
    __shared__ unsigned short Bs[128 * 32];
    int tid  = threadIdx.x;
    int wave = tid >> 6, lane = tid & 63;
    int quad = lane >> 4, l16 = lane & 15;
    int m0 = blockIdx.x * 128, n0 = blockIdx.y * 128;
    int wr = (wave >> 1) * 64, wc = (wave & 1) * 64;

    f32x4 acc[4][4] = {};

    int cA = tid, cB = tid + 256;
    int rA0 = cA >> 2, kA0 = (cA & 3) * 8;
    int rB0 = cB >> 2, kB0 = (cB & 3) * 8;
    int rA = m0 + rA0; if (rA >= M) rA = M - 1;
    int rB = m0 + rB0; if (rB >= M) rB = M - 1;
    const unsigned short* gA0 = A + (size_t)rA * K + kA0;
    const unsigned short* gA1 = A + (size_t)rB * K + kB0;
    const unsigned short* gB0 = Bt + (size_t)(n0 + rA0) * K + kA0;
    const unsigned short* gB1 = Bt + (size_t)(n0 + rB0) * K + kB0;

    for (int k0 = 0; k0 < K; k0 += 32) {
        ((uint4*)As)[cA] = *(const uint4*)(gA0 + k0);
        ((uint4*)As)[cB] = *(const uint4*)(gA1 + k0);
        ((uint4*)Bs)[cA] = *(const uint4*)(gB0 + k0);
        ((uint4*)Bs)[cB] = *(const uint4*)(gB1 + k0);
        __syncthreads();
        short8 af[4], bfr[4];
        #pragma unroll
        for (int i = 0; i < 4; ++i)
            af[i] = *(const short8*)(As + (wr + i * 16 + l16) * 32 + quad * 8);
        #pragma unroll
        for (int j = 0; j < 4; ++j)
            bfr[j] = *(const short8*)(Bs + (wc + j * 16 + l16) * 32 + quad * 8);
        #pragma unroll
        for (int i = 0; i < 4; ++i)
            #pragma unroll
            for (int j = 0; j < 4; ++j)
                acc[i][j] = __builtin_amdgcn_mfma_f32_16x16x32_bf16(
                    af[i], bfr[j], acc[i][j], 0, 0, 0);
        __syncthreads();
    }

    #pragma unroll
    for (int i = 0; i < 4; ++i) {
        #pragma unroll
        for (int j = 0; j < 4; ++j) {
            int col = n0 + wc + j * 16 + l16;
            float bsv = bias ? bias[col] : 0.0f;
            #pragma unroll
            for (int r = 0; r < 4; ++r) {
                int row = m0 + wr + i * 16 + quad * 4 + r;
                if (row < M) {
                    float v = acc[i][j][r] + bsv;
                    if (relu) v = fmaxf(v, 0.0f);
                    if (add)  v += add[(size_t)row * N + col];
                    if (Cf) Cf[(size_t)row * N + col] = v;
                    else    Cb[(size_t)row * N + col] = f2bf(v);
                }
            }
        }
    }
}

// ---------------------------------------------------------------------------
// 64x128-tile variant: 4 waves, 4x2 frags, LDS 12 KB -> more blocks/CU.
// ---------------------------------------------------------------------------
__global__ __launch_bounds__(256) void mfma_gemm64_bt(
    const unsigned short* __restrict__ A, const unsigned short* __restrict__ Bt,
    const float* __restrict__ bias, const float* __restrict__ add,
    float* __restrict__ Cf, unsigned short* __restrict__ Cb,
    int M, int K, int N, int relu)
{
    __shared__ unsigned short As[64 * 32];
    __shared__ unsigned short Bs[128 * 32];
    int tid  = threadIdx.x;
    int wave = tid >> 6, lane = tid & 63;
    int quad = lane >> 4, l16 = lane & 15;
    int m0 = blockIdx.x * 64, n0 = blockIdx.y * 128;
    int wc = wave * 32;

    f32x4 acc[4][2] = {};

    int rA0 = tid >> 2, kA0 = (tid & 3) * 8;
    int cB0 = tid, cB1 = tid + 256;
    int rB0 = cB0 >> 2, kB0 = (cB0 & 3) * 8;
    int rB1 = cB1 >> 2, kB1 = (cB1 & 3) * 8;
    int rA = m0 + rA0; if (rA >= M) rA = M - 1;
    const unsigned short* gA  = A + (size_t)rA * K + kA0;
    const unsigned short* gB0 = Bt + (size_t)(n0 + rB0) * K + kB0;
    const unsigned short* gB1 = Bt + (size_t)(n0 + rB1) * K + kB1;

    for (int k0 = 0; k0 < K; k0 += 32) {
        ((uint4*)As)[tid] = *(const uint4*)(gA + k0);
        ((uint4*)Bs)[cB0] = *(const uint4*)(gB0 + k0);
        ((uint4*)Bs)[cB1] = *(const uint4*)(gB1 + k0);
        __syncthreads();
        short8 af[4], bfr[2];
        #pragma unroll
        for (int i = 0; i < 4; ++i)
            af[i] = *(const short8*)(As + (i * 16 + l16) * 32 + quad * 8);
        #pragma unroll
        for (int j = 0; j < 2; ++j)
            bfr[j] = *(const short8*)(Bs + (wc + j * 16 + l16) * 32 + quad * 8);
        #pragma unroll
        for (int i = 0; i < 4; ++i)
            #pragma unroll
            for (int j = 0; j < 2; ++j)
                acc[i][j] = __builtin_amdgcn_mfma_f32_16x16x32_bf16(
                    af[i], bfr[j], acc[i][j], 0, 0, 0);
        __syncthreads();
    }

    #pragma unroll
    for (int i = 0; i < 4; ++i) {
        #pragma unroll
        for (int j = 0; j < 2; ++j) {
            int col = n0 + wc + j * 16 + l16;
            float bsv = bias ? bias[col] : 0.0f;
            #pragma unroll
            for (int r = 0; r < 4; ++r) {
                int row = m0 + i * 16 + quad * 4 + r;
                if (row < M) {
                    float v = acc[i][j][r] + bsv;
                    if (relu) v = fmaxf(v, 0.0f);
                    if (add)  v += add[(size_t)row * N + col];
                    if (Cf) Cf[(size_t)row * N + col] = v;
                    else    Cb[(size_t)row * N + col] = f2bf(v);
                }
            }
        }
    }
}

// ---------------------------------------------------------------------------
// Graph plumbing: degree count -> 3-phase parallel scan -> scatter
// ---------------------------------------------------------------------------
__global__ void count_kernel(const int* __restrict__ dst, int* __restrict__ deg, int E)
{
    int i = blockIdx.x * blockDim.x + threadIdx.x;
    if (i < E) atomicAdd(&deg[dst[i]], 1);
}

__global__ __launch_bounds__(256) void scan1_kernel(
    const int* __restrict__ deg, int* __restrict__ offsets, int* __restrict__ bsum, int n)
{
    __shared__ int tmp[256];
    int tid = threadIdx.x;
    int i = blockIdx.x * 256 + tid;
    int v = (i < n) ? deg[i] : 0;
    tmp[tid] = v;
    __syncthreads();
    for (int d = 1; d < 256; d <<= 1) {
        int u = (tid >= d) ? tmp[tid - d] : 0;
        __syncthreads();
        tmp[tid] += u;
        __syncthreads();
    }
    if (i < n) offsets[i] = tmp[tid] - v;
    if (tid == 255) bsum[blockIdx.x] = tmp[255];
}

__global__ __launch_bounds__(128) void scan2_kernel(int* __restrict__ bsum, int nb)
{
    __shared__ int tmp[128];
    int tid = threadIdx.x;
    int v = (tid < nb) ? bsum[tid] : 0;
    tmp[tid] = v;
    __syncthreads();
    for (int d = 1; d < 128; d <<= 1) {
        int u = (tid >= d) ? tmp[tid - d] : 0;
        __syncthreads();
        tmp[tid] += u;
        __syncthreads();
    }
    if (tid < nb) bsum[tid] = tmp[tid] - v;
}

__global__ __launch_bounds__(256) void scan3_kernel(
    const int* __restrict__ deg, int* __restrict__ offsets,
    const int* __restrict__ bsum, int* __restrict__ cursor,
    float* __restrict__ logdeg, int n, int E)
{
    int i = blockIdx.x * 256 + threadIdx.x;
    if (i < n) {
        int o = offsets[i] + bsum[blockIdx.x];
        offsets[i] = o;
        cursor[i]  = o;
        logdeg[i]  = logf((float)deg[i]);
    }
    if (i == 0) offsets[n] = E;
}

__global__ void scatter_kernel(const int* __restrict__ dst, const int* __restrict__ src,
                               const int* __restrict__ rid, int* __restrict__ cursor,
                               int* __restrict__ csr_src, int* __restrict__ csr_rid, int E)
{
    int i = blockIdx.x * blockDim.x + threadIdx.x;
    if (i < E) {
        int p = atomicAdd(&cursor[dst[i]], 1);
        csr_src[p] = src[i];
        csr_rid[p] = rid[i];
    }
}

// ---------------------------------------------------------------------------
// CSR edge attention + fused softmax. One wave per dst node (4/block).
// 16 lanes per edge, 8 edges in flight. Writes normalized weights HEAD-MAJOR:
// aH[h][e] (for per-XCD L2 locality in diffusion).
// ---------------------------------------------------------------------------
__global__ __launch_bounds__(256) void edge_score_csr_kernel(
    const unsigned short* __restrict__ proj,   // [N,768]: fh | ftl | fen
    const unsigned short* __restrict__ frel,   // [R,256] bf16
    const float* __restrict__ attn,
    const int* __restrict__ csr_src, const int* __restrict__ csr_rid,
    const int* __restrict__ offsets, const float* __restrict__ logdeg,
    float* __restrict__ aH, int n)
{
    int node = blockIdx.x * 4 + (threadIdx.x >> 6);
    if (node >= n) return;
    int tid = threadIdx.x & 63;
    int g = tid >> 4, li = tid & 15;
    int start = offsets[node], end = offsets[node + 1];
    float scale = logdeg[node] * (1.0f / 32.0f);

    float tv[16], at[16];
    {
        const unsigned short* tp = proj + (size_t)node * 768 + 256 + li * 16;
        uint4 a0 = *(const uint4*)tp, a1 = *(const uint4*)(tp + 8);
        unpack8(tv, a0); unpack8(tv + 8, a1);
        const float4* ap = (const float4*)(attn + li * 16);
        float4 f;
        f = ap[0]; at[0] = f.x; at[1] = f.y; at[2]  = f.z; at[3]  = f.w;
        f = ap[1]; at[4] = f.x; at[5] = f.y; at[6]  = f.z; at[7]  = f.w;
        f = ap[2]; at[8] = f.x; at[9] = f.y; at[10] = f.z; at[11] = f.w;
        f = ap[3]; at[12] = f.x; at[13] = f.y; at[14] = f.z; at[15] = f.w;
    }

    float denom = 0.f;
    for (int p = start; p < end; p += 8) {
        int  pe[2]; bool va[2]; uint4 h0[2], h1[2], r0[2], r1[2];
        #pragma unroll
        for (int t = 0; t < 2; ++t) {
            pe[t] = p + t * 4 + g;
            va[t] = pe[t] < end;
            int q = va[t] ? pe[t] : end - 1;
            int s = csr_src[q], r = csr_rid[q];
            const unsigned short* hp = proj + (size_t)s * 768 + li * 16;
            const unsigned short* rp = frel + (size_t)r * FDIM + li * 16;
            h0[t] = *(const uint4*)hp; h1[t] = *(const uint4*)(hp + 8);
            r0[t] = *(const uint4*)rp; r1[t] = *(const uint4*)(rp + 8);
        }
        #pragma unroll
        for (int t = 0; t < 2; ++t) {
            float hv[16], rv[16];
            unpack8(hv, h0[t]); unpack8(hv + 8, h1[t]);
            unpack8(rv, r0[t]); unpack8(rv + 8, r1[t]);
            float sum = 0.f;
            #pragma unroll
            for (int k = 0; k < 16; ++k) {
                float m = hv[k] * tv[k] * rv[k];
                m = (m > 0.f) ? m : 0.2f * m;
                sum += m * at[k];
            }
            sum += __shfl_xor(sum, 1);
            float ex = expf(sum * scale);
            if (va[t] && ((li & 1) == 0)) {
                aH[(size_t)(li >> 1) * N_EDGES + pe[t]] = ex;
                denom += ex;
            }
        }
    }
    denom += __shfl_xor(denom, 16);
    denom += __shfl_xor(denom, 32);
    #pragma unroll
    for (int h2 = 0; h2 < 8; ++h2) {
        float inv = 1.0f / __shfl(denom, 2 * h2);
        for (int e = start + tid; e < end; e += 64)
            aH[(size_t)h2 * N_EDGES + e] *= inv;
    }
}

// ---------------------------------------------------------------------------
// One PPR hop, head-major: F[h][n][32] bf16. head = blockIdx % 8 -> all
// blocks of one head land on one XCD (round-robin heuristic); the 1.25 MB
// head slice + indices + weights fit that XCD's 4 MB L2.
// Wave = one node; 16 lanes (dwords) per edge row, 4 edges/wave, 4-deep unroll.
// ---------------------------------------------------------------------------
__global__ __launch_bounds__(256) void diffuse_h_kernel(
    const unsigned short* __restrict__ fin,    // [8][n][32]
    const unsigned short* __restrict__ feat0,  // [8][n][32]
    const float* __restrict__ aH,              // [8][E]
    const int* __restrict__ csr_src, const int* __restrict__ offsets,
    unsigned short* __restrict__ fout, int n)
{
    int h = blockIdx.x & 7;
    int node = (blockIdx.x >> 3) * 4 + (threadIdx.x >> 6);
    if (node >= n) return;
    int tid = threadIdx.x & 63;
    int g = tid >> 4, li = tid & 15;
    int start = offsets[node], end = offsets[node + 1];
    const unsigned int* finh = (const unsigned int*)fin + (size_t)h * n * 16;
    const float* ah = aH + (size_t)h * N_EDGES;
    float ax = 0.f, ay = 0.f;
    for (int p = start; p < end; p += 16) {
        unsigned int u[4]; float w[4];
        #pragma unroll
        for (int t = 0; t < 4; ++t) {
            int pe = p + t * 4 + g;
            int q = (pe < end) ? pe : end - 1;
            int s = csr_src[q];
            w[t] = (pe < end) ? ah[q] : 0.0f;
            u[t] = finh[s * 16 + li];
        }
        #pragma unroll
        for (int t = 0; t < 4; ++t) {
            union { unsigned int u; float f; } lo, hi;
            lo.u = u[t] << 16; hi.u = u[t] & 0xffff0000u;
            ax += w[t] * lo.f; ay += w[t] * hi.f;
        }
    }
    ax += __shfl_xor(ax, 16); ax += __shfl_xor(ax, 32);
    ay += __shfl_xor(ay, 16); ay += __shfl_xor(ay, 32);
    if (g == 0) {
        unsigned int f0 = ((const unsigned int*)feat0)[((size_t)h * n + node) * 16 + li];
        union { unsigned int u; float f; } lo, hi;
        lo.u = f0 << 16; hi.u = f0 & 0xffff0000u;
        unsigned int o = (unsigned int)f2bf(0.9f * ax + 0.1f * lo.f)
                       | ((unsigned int)f2bf(0.9f * ay + 0.1f * hi.f) << 16);
        ((unsigned int*)fout)[((size_t)h * n + node) * 16 + li] = o;
    }
}

// ---------------------------------------------------------------------------
extern "C" void kernel_launch(void* const* d_in, const int* in_sizes, int n_in,
                              void* d_out, int out_size, void* d_ws, size_t ws_size,
                              hipStream_t stream)
{
    const float* ent_feat = (const float*)d_in[0];
    const float* rel_feat = (const float*)d_in[1];
    const float* W_head   = (const float*)d_in[2];
    const float* W_tail   = (const float*)d_in[3];
    const float* W_ent    = (const float*)d_in[4];
    const float* W_rel    = (const float*)d_in[5];
    const float* attn     = (const float*)d_in[6];
    const float* ln_ent_g = (const float*)d_in[7];
    const float* ln_ent_b = (const float*)d_in[8];
    const float* ln_rel_g = (const float*)d_in[9];
    const float* ln_rel_b = (const float*)d_in[10];
    const float* ln_ff_g  = (const float*)d_in[11];
    const float* ln_ff_b  = (const float*)d_in[12];
    const float* W1       = (const float*)d_in[13];
    const float* b1       = (const float*)d_in[14];
    const float* W2       = (const float*)d_in[15];
    const float* b2       = (const float*)d_in[16];
    const int*   src      = (const int*)d_in[17];
    const int*   dst      = (const int*)d_in[18];
    const int*   rid      = (const int*)d_in[19];
    float* out = (float*)d_out;

    // ---- workspace carve (bytes, 256-aligned) ----
    char* base = (char*)d_ws;
    auto carve = [&](size_t bytes) { char* p = base; base += (bytes + 255) & ~(size_t)255; return p; };
    unsigned short* xb    = (unsigned short*)carve((size_t)N_NODES * FDIM * 2);
    unsigned short* projb = (unsigned short*)carve((size_t)N_NODES * 768 * 2);
    unsigned short* rlnb  = (unsigned short*)carve((size_t)N_REL * FDIM * 2);
    unsigned short* frelb = (unsigned short*)carve((size_t)N_REL * FDIM * 2);
    unsigned short* WtP   = (unsigned short*)carve((size_t)768 * FDIM * 2);
    unsigned short* WtR   = (unsigned short*)carve((size_t)FDIM * FDIM * 2);
    unsigned short* W1t   = (unsigned short*)carve((size_t)1024 * FDIM * 2);
    unsigned short* W2t   = (unsigned short*)carve((size_t)FDIM * 1024 * 2);
    unsigned short* F0H   = (unsigned short*)carve((size_t)N_NODES * FDIM * 2);  // head-major fen
    unsigned short* hbH0  = (unsigned short*)carve((size_t)N_NODES * FDIM * 2);  // head-major hops
    unsigned short* hbH1  = (unsigned short*)carve((size_t)N_NODES * FDIM * 2);
    unsigned short* yb    = (unsigned short*)carve((size_t)N_NODES * FDIM * 2);
    unsigned short* t1b   = (unsigned short*)carve((size_t)N_NODES * 1024 * 2);
    float* rst     = (float*)carve((size_t)N_NODES * FDIM * 4);
    float* aH      = (float*)carve((size_t)N_EDGES * NHEAD * 4);   // head-major weights
    int*   csr_src = (int*)carve((size_t)(N_EDGES + 64) * 4);
    int*   csr_rid = (int*)carve((size_t)(N_EDGES + 64) * 4);
    int*   deg     = (int*)carve((size_t)N_NODES * 4);
    float* logdeg  = (float*)carve((size_t)N_NODES * 4);
    int*   offsets = (int*)carve((size_t)(N_NODES + 1) * 4);
    int*   cursor  = (int*)carve((size_t)N_NODES * 4);
    int*   bsum    = (int*)carve((size_t)SCAN_BLOCKS * 4);

    hipMemsetAsync(deg, 0, (size_t)N_NODES * 4, stream);

    // LN -> bf16
    ln_bf16_kernel<<<N_NODES, 64, 0, stream>>>(ent_feat, ln_ent_g, ln_ent_b, xb, N_NODES);
    ln_bf16_kernel<<<N_REL, 64, 0, stream>>>(rel_feat, ln_rel_g, ln_rel_b, rlnb, N_REL);

    // weight transposes (fp32 [K,N] -> bf16 [N,K]); WtP rows = [head | tail | ent]
    transpose_bf16_kernel<<<(65536 + 255) / 256, 256, 0, stream>>>(W_head, WtP,              FDIM, FDIM);
    transpose_bf16_kernel<<<(65536 + 255) / 256, 256, 0, stream>>>(W_tail, WtP + 256 * FDIM, FDIM, FDIM);
    transpose_bf16_kernel<<<(65536 + 255) / 256, 256, 0, stream>>>(W_ent,  WtP + 512 * FDIM, FDIM, FDIM);
    transpose_bf16_kernel<<<(65536 + 255) / 256, 256, 0, stream>>>(W_rel,  WtR, FDIM, FDIM);
    transpose_bf16_kernel<<<(262144 + 255) / 256, 256, 0, stream>>>(W1, W1t, FDIM, 1024);
    transpose_bf16_kernel<<<(262144 + 255) / 256, 256, 0, stream>>>(W2, W2t, 1024, FDIM);

    // fused projection GEMM: proj[N,768] = xb @ [Wh|Wt|We]  (bf16 out)
    dim3 gproj((N_NODES + 127) / 128, 768 / 128);
    mfma_gemm_bt<<<gproj, 256, 0, stream>>>(xb, WtP, nullptr, nullptr, nullptr, projb,
                                            N_NODES, FDIM, 768, 0);
    dim3 grel(1, FDIM / 128);
    mfma_gemm_bt<<<grel, 256, 0, stream>>>(rlnb, WtR, nullptr, nullptr, nullptr, frelb,
                                           N_REL, FDIM, FDIM, 0);

    // repack fen -> head-major F0H
    repack_fen_kernel<<<(N_NODES * 128 + 255) / 256, 256, 0, stream>>>(projb, F0H, N_NODES);

    // CSR build (count -> 3-phase parallel scan -> scatter)
    count_kernel<<<(N_EDGES + 255) / 256, 256, 0, stream>>>(dst, deg, N_EDGES);
    scan1_kernel<<<SCAN_BLOCKS, 256, 0, stream>>>(deg, offsets, bsum, N_NODES);
    scan2_kernel<<<1, 128, 0, stream>>>(bsum, SCAN_BLOCKS);
    scan3_kernel<<<SCAN_BLOCKS, 256, 0, stream>>>(deg, offsets, bsum, cursor, logdeg,
                                                  N_NODES, N_EDGES);
    scatter_kernel<<<(N_EDGES + 255) / 256, 256, 0, stream>>>(dst, src, rid, cursor,
                                                              csr_src, csr_rid, N_EDGES);

    // attention + fused softmax (normalized weights, head-major)
    edge_score_csr_kernel<<<(N_NODES + 3) / 4, 256, 0, stream>>>(
        projb, frelb, attn, csr_src, csr_rid, offsets, logdeg, aH, N_NODES);

    // 5-hop PPR diffusion, head-major with XCD affinity:
    // F0H -> hbH0 -> hbH1 -> hbH0 -> hbH1 -> hbH0
    int gdif = ((N_NODES + 3) / 4) * 8;
    diffuse_h_kernel<<<gdif, 256, 0, stream>>>(F0H,  F0H, aH, csr_src, offsets, hbH0, N_NODES);
    diffuse_h_kernel<<<gdif, 256, 0, stream>>>(hbH0, F0H, aH, csr_src, offsets, hbH1, N_NODES);
    diffuse_h_kernel<<<gdif, 256, 0, stream>>>(hbH1, F0H, aH, csr_src, offsets, hbH0, N_NODES);
    diffuse_h_kernel<<<gdif, 256, 0, stream>>>(hbH0, F0H, aH, csr_src, offsets, hbH1, N_NODES);
    diffuse_h_kernel<<<gdif, 256, 0, stream>>>(hbH1, F0H, aH, csr_src, offsets, hbH0, N_NODES);

    // residual + pre-LN (reads head-major hbH0)
    rst_ln_kernel<<<N_NODES, 64, 0, stream>>>(hbH0, ent_feat, ln_ff_g, ln_ff_b, rst, yb);

    // FFN1: t1 = relu(y@W1 + b1) [bf16], 64x128 tiles (2504 blocks)
    dim3 gff1((N_NODES + 63) / 64, 1024 / 128);
    mfma_gemm64_bt<<<gff1, 256, 0, stream>>>(yb, W1t, b1, nullptr, nullptr, t1b,
                                             N_NODES, FDIM, 1024, 1);
    // FFN2: out = t1@W2 + b2 + rst, 64x128 tiles
    dim3 gff2((N_NODES + 63) / 64, FDIM / 128);
    mfma_gemm64_bt<<<gff2, 256, 0, stream>>>(t1b, W2t, b2, rst, out, nullptr,
                                             N_NODES, 1024, FDIM, 0);
}

// Round 11
// 660.882 us; speedup vs baseline: 1.0559x; 1.0559x over previous
//
#include <hip/hip_runtime.h>

#define N_NODES 20000
#define N_EDGES 320000
#define N_REL   100
#define FDIM    256
#define NHEAD   8
#define HDIM    32
#define SCAN_BLOCKS ((N_NODES + 255) / 256)   // 79

using short8 = __attribute__((ext_vector_type(8))) short;   // 8 bf16 in 4 VGPRs
using f32x4  = __attribute__((ext_vector_type(4))) float;

__device__ inline unsigned short f2bf(float f) {
    union { float f; unsigned int u; } v; v.f = f;
    unsigned int r = v.u + 0x7fff + ((v.u >> 16) & 1);   // RNE
    return (unsigned short)(r >> 16);
}
__device__ inline float bf2f(unsigned short u) {
    union { unsigned int i; float f; } v; v.i = ((unsigned int)u) << 16; return v.f;
}
__device__ inline float4 bf4(ushort4 u) {
    return make_float4(bf2f(u.x), bf2f(u.y), bf2f(u.z), bf2f(u.w));
}
// unpack 8 bf16 (uint4) -> 8 fp32
__device__ inline void unpack8(float* d, uint4 u) {
    union { unsigned int u; float f; } t;
    t.u = u.x << 16;         d[0] = t.f;
    t.u = u.x & 0xffff0000u; d[1] = t.f;
    t.u = u.y << 16;         d[2] = t.f;
    t.u = u.y & 0xffff0000u; d[3] = t.f;
    t.u = u.z << 16;         d[4] = t.f;
    t.u = u.z & 0xffff0000u; d[5] = t.f;
    t.u = u.w << 16;         d[6] = t.f;
    t.u = u.w & 0xffff0000u; d[7] = t.f;
}
// acc[k] += w * bf16(u)[k], 8 elements
__device__ inline void fma8(float* acc, uint4 u, float w) {
    union { unsigned int u; float f; } t;
    t.u = u.x << 16;         acc[0] += w * t.f;
    t.u = u.x & 0xffff0000u; acc[1] += w * t.f;
    t.u = u.y << 16;         acc[2] += w * t.f;
    t.u = u.y & 0xffff0000u; acc[3] += w * t.f;
    t.u = u.z << 16;         acc[4] += w * t.f;
    t.u = u.z & 0xffff0000u; acc[5] += w * t.f;
    t.u = u.w << 16;         acc[6] += w * t.f;
    t.u = u.w & 0xffff0000u; acc[7] += w * t.f;
}

// ---------------------------------------------------------------------------
// LayerNorm over 256 features -> bf16 output. One wave per row.
// ---------------------------------------------------------------------------
__global__ __launch_bounds__(64) void ln_bf16_kernel(
    const float* __restrict__ in, const float* __restrict__ g,
    const float* __restrict__ b, unsigned short* __restrict__ out, int rows)
{
    int row = blockIdx.x;
    if (row >= rows) return;
    int tid = threadIdx.x;
    const float4 v = *(const float4*)(in + (size_t)row * FDIM + tid * 4);
    float s = v.x + v.y + v.z + v.w;
    float q = v.x * v.x + v.y * v.y + v.z * v.z + v.w * v.w;
    #pragma unroll
    for (int d = 1; d < 64; d <<= 1) { s += __shfl_xor(s, d); q += __shfl_xor(q, d); }
    float mean = s * (1.0f / FDIM);
    float var  = q * (1.0f / FDIM) - mean * mean;
    float inv  = rsqrtf(var + 1e-5f);
    float4 gg = *(const float4*)(g + tid * 4);
    float4 bb = *(const float4*)(b + tid * 4);
    ushort4 o;
    o.x = f2bf((v.x - mean) * inv * gg.x + bb.x);
    o.y = f2bf((v.y - mean) * inv * gg.y + bb.y);
    o.z = f2bf((v.z - mean) * inv * gg.z + bb.z);
    o.w = f2bf((v.w - mean) * inv * gg.w + bb.w);
    *(ushort4*)(out + (size_t)row * FDIM + tid * 4) = o;
}

// rst = bf2f(featH) + ent (fp32) ; y = LN(rst) (bf16). featH is head-major [8][N][32].
__global__ __launch_bounds__(64) void rst_ln_kernel(
    const unsigned short* __restrict__ featH, const float* __restrict__ ent,
    const float* __restrict__ g, const float* __restrict__ b,
    float* __restrict__ rst, unsigned short* __restrict__ y)
{
    int row = blockIdx.x;
    int tid = threadIdx.x;
    int h = tid >> 3;                      // head of dims tid*4..tid*4+3
    const ushort4 fu = *(const ushort4*)(featH + ((size_t)h * N_NODES + row) * 32 + (tid & 7) * 4);
    const float4 f = bf4(fu);
    const float4 e = *(const float4*)(ent + (size_t)row * FDIM + tid * 4);
    float4 r;
    r.x = f.x + e.x; r.y = f.y + e.y; r.z = f.z + e.z; r.w = f.w + e.w;
    *(float4*)(rst + (size_t)row * FDIM + tid * 4) = r;
    float s = r.x + r.y + r.z + r.w;
    float q = r.x * r.x + r.y * r.y + r.z * r.z + r.w * r.w;
    #pragma unroll
    for (int d = 1; d < 64; d <<= 1) { s += __shfl_xor(s, d); q += __shfl_xor(q, d); }
    float mean = s * (1.0f / FDIM);
    float var  = q * (1.0f / FDIM) - mean * mean;
    float inv  = rsqrtf(var + 1e-5f);
    float4 gg = *(const float4*)(g + tid * 4);
    float4 bb = *(const float4*)(b + tid * 4);
    ushort4 o;
    o.x = f2bf((r.x - mean) * inv * gg.x + bb.x);
    o.y = f2bf((r.y - mean) * inv * gg.y + bb.y);
    o.z = f2bf((r.z - mean) * inv * gg.z + bb.z);
    o.w = f2bf((r.w - mean) * inv * gg.w + bb.w);
    *(ushort4*)(y + (size_t)row * FDIM + tid * 4) = o;
}

// Wt[n*K + k] = bf16(W[k*N + n])
__global__ void transpose_bf16_kernel(const float* __restrict__ W,
                                      unsigned short* __restrict__ Wt, int K, int N)
{
    int idx = blockIdx.x * 256 + threadIdx.x;
    if (idx >= K * N) return;
    int n = idx / K, k = idx - n * K;
    Wt[idx] = f2bf(W[(size_t)k * N + n]);
}

// repack fen (projb cols 512..767, row-major) -> F0 head-major [8][N][32], dword granularity
__global__ void repack_fen_kernel(const unsigned short* __restrict__ projb,
                                  unsigned short* __restrict__ F0, int n)
{
    int idx = blockIdx.x * 256 + threadIdx.x;
    int total = n * 128;                 // dwords
    if (idx >= total) return;
    int row = idx >> 7, d2 = idx & 127;  // d2: dword in row (2 dims)
    int h = d2 >> 4, w = d2 & 15;
    ((unsigned int*)F0)[((size_t)h * n + row) * 16 + w] =
        ((const unsigned int*)projb)[(size_t)row * 384 + 256 + d2];
}

// ---------------------------------------------------------------------------
// bf16 MFMA GEMM (B^T): 128x128 tile, 4 waves, 4x4 frags, BK=32.
// ---------------------------------------------------------------------------
__global__ __launch_bounds__(256) void mfma_gemm_bt(
    const unsigned short* __restrict__ A, const unsigned short* __restrict__ Bt,
    const float* __restrict__ bias, const float* __restrict__ add,
    float* __restrict__ Cf, unsigned short* __restrict__ Cb,
    int M, int K, int N, int relu)
{
    __shared__ unsigned short As[128 * 32];
    __shared__ unsigned short Bs[128 * 32];
    int tid  = threadIdx.x;
    int wave = tid >> 6, lane = tid & 63;
    int quad = lane >> 4, l16 = lane & 15;
    int m0 = blockIdx.x * 128, n0 = blockIdx.y * 128;
    int wr = (wave >> 1) * 64, wc = (wave & 1) * 64;

    f32x4 acc[4][4] = {};

    int cA = tid, cB = tid + 256;
    int rA0 = cA >> 2, kA0 = (cA & 3) * 8;
    int rB0 = cB >> 2, kB0 = (cB & 3) * 8;
    int rA = m0 + rA0; if (rA >= M) rA = M - 1;
    int rB = m0 + rB0; if (rB >= M) rB = M - 1;
    const unsigned short* gA0 = A + (size_t)rA * K + kA0;
    const unsigned short* gA1 = A + (size_t)rB * K + kB0;
    const unsigned short* gB0 = Bt + (size_t)(n0 + rA0) * K + kA0;
    const unsigned short* gB1 = Bt + (size_t)(n0 + rB0) * K + kB0;

    for (int k0 = 0; k0 < K; k0 += 32) {
        ((uint4*)As)[cA] = *(const uint4*)(gA0 + k0);
        ((uint4*)As)[cB] = *(const uint4*)(gA1 + k0);
        ((uint4*)Bs)[cA] = *(const uint4*)(gB0 + k0);
        ((uint4*)Bs)[cB] = *(const uint4*)(gB1 + k0);
        __syncthreads();
        short8 af[4], bfr[4];
        #pragma unroll
        for (int i = 0; i < 4; ++i)
            af[i] = *(const short8*)(As + (wr + i * 16 + l16) * 32 + quad * 8);
        #pragma unroll
        for (int j = 0; j < 4; ++j)
            bfr[j] = *(const short8*)(Bs + (wc + j * 16 + l16) * 32 + quad * 8);
        #pragma unroll
        for (int i = 0; i < 4; ++i)
            #pragma unroll
            for (int j = 0; j < 4; ++j)
                acc[i][j] = __builtin_amdgcn_mfma_f32_16x16x32_bf16(
                    af[i], bfr[j], acc[i][j], 0, 0, 0);
        __syncthreads();
    }

    #pragma unroll
    for (int i = 0; i < 4; ++i) {
        #pragma unroll
        for (int j = 0; j < 4; ++j) {
            int col = n0 + wc + j * 16 + l16;
            float bsv = bias ? bias[col] : 0.0f;
            #pragma unroll
            for (int r = 0; r < 4; ++r) {
                int row = m0 + wr + i * 16 + quad * 4 + r;
                if (row < M) {
                    float v = acc[i][j][r] + bsv;
                    if (relu) v = fmaxf(v, 0.0f);
                    if (add)  v += add[(size_t)row * N + col];
                    if (Cf) Cf[(size_t)row * N + col] = v;
                    else    Cb[(size_t)row * N + col] = f2bf(v);
                }
            }
        }
    }
}

// ---------------------------------------------------------------------------
// 64x128-tile variant: 4 waves, 4x2 frags, LDS 12 KB -> more blocks/CU.
// ---------------------------------------------------------------------------
__global__ __launch_bounds__(256) void mfma_gemm64_bt(
    const unsigned short* __restrict__ A, const unsigned short* __restrict__ Bt,
    const float* __restrict__ bias, const float* __restrict__ add,
    float* __restrict__ Cf, unsigned short* __restrict__ Cb,
    int M, int K, int N, int relu)
{
    __shared__ unsigned short As[64 * 32];
    __shared__ unsigned short Bs[128 * 32];
    int tid  = threadIdx.x;
    int wave = tid >> 6, lane = tid & 63;
    int quad = lane >> 4, l16 = lane & 15;
    int m0 = blockIdx.x * 64, n0 = blockIdx.y * 128;
    int wc = wave * 32;

    f32x4 acc[4][2] = {};

    int rA0 = tid >> 2, kA0 = (tid & 3) * 8;
    int cB0 = tid, cB1 = tid + 256;
    int rB0 = cB0 >> 2, kB0 = (cB0 & 3) * 8;
    int rB1 = cB1 >> 2, kB1 = (cB1 & 3) * 8;
    int rA = m0 + rA0; if (rA >= M) rA = M - 1;
    const unsigned short* gA  = A + (size_t)rA * K + kA0;
    const unsigned short* gB0 = Bt + (size_t)(n0 + rB0) * K + kB0;
    const unsigned short* gB1 = Bt + (size_t)(n0 + rB1) * K + kB1;

    for (int k0 = 0; k0 < K; k0 += 32) {
        ((uint4*)As)[tid] = *(const uint4*)(gA + k0);
        ((uint4*)Bs)[cB0] = *(const uint4*)(gB0 + k0);
        ((uint4*)Bs)[cB1] = *(const uint4*)(gB1 + k0);
        __syncthreads();
        short8 af[4], bfr[2];
        #pragma unroll
        for (int i = 0; i < 4; ++i)
            af[i] = *(const short8*)(As + (i * 16 + l16) * 32 + quad * 8);
        #pragma unroll
        for (int j = 0; j < 2; ++j)
            bfr[j] = *(const short8*)(Bs + (wc + j * 16 + l16) * 32 + quad * 8);
        #pragma unroll
        for (int i = 0; i < 4; ++i)
            #pragma unroll
            for (int j = 0; j < 2; ++j)
                acc[i][j] = __builtin_amdgcn_mfma_f32_16x16x32_bf16(
                    af[i], bfr[j], acc[i][j], 0, 0, 0);
        __syncthreads();
    }

    #pragma unroll
    for (int i = 0; i < 4; ++i) {
        #pragma unroll
        for (int j = 0; j < 2; ++j) {
            int col = n0 + wc + j * 16 + l16;
            float bsv = bias ? bias[col] : 0.0f;
            #pragma unroll
            for (int r = 0; r < 4; ++r) {
                int row = m0 + i * 16 + quad * 4 + r;
                if (row < M) {
                    float v = acc[i][j][r] + bsv;
                    if (relu) v = fmaxf(v, 0.0f);
                    if (add)  v += add[(size_t)row * N + col];
                    if (Cf) Cf[(size_t)row * N + col] = v;
                    else    Cb[(size_t)row * N + col] = f2bf(v);
                }
            }
        }
    }
}

// ---------------------------------------------------------------------------
// Graph plumbing: degree count -> 3-phase parallel scan -> scatter
// ---------------------------------------------------------------------------
__global__ void count_kernel(const int* __restrict__ dst, int* __restrict__ deg, int E)
{
    int i = blockIdx.x * blockDim.x + threadIdx.x;
    if (i < E) atomicAdd(&deg[dst[i]], 1);
}

__global__ __launch_bounds__(256) void scan1_kernel(
    const int* __restrict__ deg, int* __restrict__ offsets, int* __restrict__ bsum, int n)
{
    __shared__ int tmp[256];
    int tid = threadIdx.x;
    int i = blockIdx.x * 256 + tid;
    int v = (i < n) ? deg[i] : 0;
    tmp[tid] = v;
    __syncthreads();
    for (int d = 1; d < 256; d <<= 1) {
        int u = (tid >= d) ? tmp[tid - d] : 0;
        __syncthreads();
        tmp[tid] += u;
        __syncthreads();
    }
    if (i < n) offsets[i] = tmp[tid] - v;
    if (tid == 255) bsum[blockIdx.x] = tmp[255];
}

__global__ __launch_bounds__(128) void scan2_kernel(int* __restrict__ bsum, int nb)
{
    __shared__ int tmp[128];
    int tid = threadIdx.x;
    int v = (tid < nb) ? bsum[tid] : 0;
    tmp[tid] = v;
    __syncthreads();
    for (int d = 1; d < 128; d <<= 1) {
        int u = (tid >= d) ? tmp[tid - d] : 0;
        __syncthreads();
        tmp[tid] += u;
        __syncthreads();
    }
    if (tid < nb) bsum[tid] = tmp[tid] - v;
}

__global__ __launch_bounds__(256) void scan3_kernel(
    const int* __restrict__ deg, int* __restrict__ offsets,
    const int* __restrict__ bsum, int* __restrict__ cursor,
    float* __restrict__ logdeg, int n, int E)
{
    int i = blockIdx.x * 256 + threadIdx.x;
    if (i < n) {
        int o = offsets[i] + bsum[blockIdx.x];
        offsets[i] = o;
        cursor[i]  = o;
        logdeg[i]  = logf((float)deg[i]);
    }
    if (i == 0) offsets[n] = E;
}

__global__ void scatter_kernel(const int* __restrict__ dst, const int* __restrict__ src,
                               const int* __restrict__ rid, int* __restrict__ cursor,
                               int* __restrict__ csr_src, int* __restrict__ csr_rid, int E)
{
    int i = blockIdx.x * blockDim.x + threadIdx.x;
    if (i < E) {
        int p = atomicAdd(&cursor[dst[i]], 1);
        csr_src[p] = src[i];
        csr_rid[p] = rid[i];
    }
}

// ---------------------------------------------------------------------------
// CSR edge attention + fused softmax. One wave per dst node (4/block).
// 16 lanes per edge, 8 edges in flight. Writes normalized weights HEAD-MAJOR:
// aH[h][e] (for per-XCD L2 locality in diffusion).
// ---------------------------------------------------------------------------
__global__ __launch_bounds__(256) void edge_score_csr_kernel(
    const unsigned short* __restrict__ proj,   // [N,768]: fh | ftl | fen
    const unsigned short* __restrict__ frel,   // [R,256] bf16
    const float* __restrict__ attn,
    const int* __restrict__ csr_src, const int* __restrict__ csr_rid,
    const int* __restrict__ offsets, const float* __restrict__ logdeg,
    float* __restrict__ aH, int n)
{
    int node = blockIdx.x * 4 + (threadIdx.x >> 6);
    if (node >= n) return;
    int tid = threadIdx.x & 63;
    int g = tid >> 4, li = tid & 15;
    int start = offsets[node], end = offsets[node + 1];
    float scale = logdeg[node] * (1.0f / 32.0f);

    float tv[16], at[16];
    {
        const unsigned short* tp = proj + (size_t)node * 768 + 256 + li * 16;
        uint4 a0 = *(const uint4*)tp, a1 = *(const uint4*)(tp + 8);
        unpack8(tv, a0); unpack8(tv + 8, a1);
        const float4* ap = (const float4*)(attn + li * 16);
        float4 f;
        f = ap[0]; at[0] = f.x; at[1] = f.y; at[2]  = f.z; at[3]  = f.w;
        f = ap[1]; at[4] = f.x; at[5] = f.y; at[6]  = f.z; at[7]  = f.w;
        f = ap[2]; at[8] = f.x; at[9] = f.y; at[10] = f.z; at[11] = f.w;
        f = ap[3]; at[12] = f.x; at[13] = f.y; at[14] = f.z; at[15] = f.w;
    }

    float denom = 0.f;
    for (int p = start; p < end; p += 8) {
        int  pe[2]; bool va[2]; uint4 h0[2], h1[2], r0[2], r1[2];
        #pragma unroll
        for (int t = 0; t < 2; ++t) {
            pe[t] = p + t * 4 + g;
            va[t] = pe[t] < end;
            int q = va[t] ? pe[t] : end - 1;
            int s = csr_src[q], r = csr_rid[q];
            const unsigned short* hp = proj + (size_t)s * 768 + li * 16;
            const unsigned short* rp = frel + (size_t)r * FDIM + li * 16;
            h0[t] = *(const uint4*)hp; h1[t] = *(const uint4*)(hp + 8);
            r0[t] = *(const uint4*)rp; r1[t] = *(const uint4*)(rp + 8);
        }
        #pragma unroll
        for (int t = 0; t < 2; ++t) {
            float hv[16], rv[16];
            unpack8(hv, h0[t]); unpack8(hv + 8, h1[t]);
            unpack8(rv, r0[t]); unpack8(rv + 8, r1[t]);
            float sum = 0.f;
            #pragma unroll
            for (int k = 0; k < 16; ++k) {
                float m = hv[k] * tv[k] * rv[k];
                m = (m > 0.f) ? m : 0.2f * m;
                sum += m * at[k];
            }
            sum += __shfl_xor(sum, 1);
            float ex = expf(sum * scale);
            if (va[t] && ((li & 1) == 0)) {
                aH[(size_t)(li >> 1) * N_EDGES + pe[t]] = ex;
                denom += ex;
            }
        }
    }
    denom += __shfl_xor(denom, 16);
    denom += __shfl_xor(denom, 32);
    #pragma unroll
    for (int h2 = 0; h2 < 8; ++h2) {
        float inv = 1.0f / __shfl(denom, 2 * h2);
        for (int e = start + tid; e < end; e += 64)
            aH[(size_t)h2 * N_EDGES + e] *= inv;
    }
}

// ---------------------------------------------------------------------------
// One PPR hop, head-major F[h][n][32] bf16, head = blockIdx % 8 (XCD affinity).
// Wave = (node, head); 4 lanes x uint4 per edge slice (16 B/lane), 16 edges
// in flight per wave. Wave-uniform fast path (2 full windows) + clamped tail.
// ---------------------------------------------------------------------------
__global__ __launch_bounds__(256) void diffuse_h_kernel(
    const unsigned short* __restrict__ fin,    // [8][n][32]
    const unsigned short* __restrict__ feat0,  // [8][n][32]
    const float* __restrict__ aH,              // [8][E]
    const int* __restrict__ csr_src, const int* __restrict__ offsets,
    unsigned short* __restrict__ fout, int n)
{
    int h = blockIdx.x & 7;
    int node = (blockIdx.x >> 3) * 4 + (threadIdx.x >> 6);
    if (node >= n) return;
    int tid = threadIdx.x & 63;
    int g = tid >> 2, li = tid & 3;        // g: edge slot 0..15, li: uint4 in 64B slice
    int start = offsets[node], end = offsets[node + 1];
    const uint4* finh = (const uint4*)fin + (size_t)h * n * 4;
    const float* ah = aH + (size_t)h * N_EDGES;
    float acc[8] = {};

    int p = start;
    for (; p + 32 <= end; p += 32) {       // wave-uniform: two full windows, no clamps
        int q0 = p + g, q1 = p + 16 + g;
        int s0 = csr_src[q0], s1 = csr_src[q1];
        float w0 = ah[q0], w1 = ah[q1];
        uint4 u0 = finh[(size_t)s0 * 4 + li];
        uint4 u1 = finh[(size_t)s1 * 4 + li];
        fma8(acc, u0, w0);
        fma8(acc, u1, w1);
    }
    for (; p < end; p += 16) {             // tail window with clamps
        int pe = p + g;
        int q = (pe < end) ? pe : end - 1;
        int s = csr_src[q];
        float w = (pe < end) ? ah[q] : 0.0f;
        uint4 u = finh[(size_t)s * 4 + li];
        fma8(acc, u, w);
    }
    // reduce over the 16 edge groups (lane bits 2..5)
    #pragma unroll
    for (int k = 0; k < 8; ++k) {
        acc[k] += __shfl_xor(acc[k], 4);
        acc[k] += __shfl_xor(acc[k], 8);
        acc[k] += __shfl_xor(acc[k], 16);
        acc[k] += __shfl_xor(acc[k], 32);
    }
    if (g == 0) {
        uint4 f0u = ((const uint4*)feat0)[((size_t)h * n + node) * 4 + li];
        float f0[8];
        unpack8(f0, f0u);
        unsigned short o[8];
        #pragma unroll
        for (int k = 0; k < 8; ++k) o[k] = f2bf(0.9f * acc[k] + 0.1f * f0[k]);
        ((uint4*)fout)[((size_t)h * n + node) * 4 + li] = *(uint4*)o;
    }
}

// ---------------------------------------------------------------------------
extern "C" void kernel_launch(void* const* d_in, const int* in_sizes, int n_in,
                              void* d_out, int out_size, void* d_ws, size_t ws_size,
                              hipStream_t stream)
{
    const float* ent_feat = (const float*)d_in[0];
    const float* rel_feat = (const float*)d_in[1];
    const float* W_head   = (const float*)d_in[2];
    const float* W_tail   = (const float*)d_in[3];
    const float* W_ent    = (const float*)d_in[4];
    const float* W_rel    = (const float*)d_in[5];
    const float* attn     = (const float*)d_in[6];
    const float* ln_ent_g = (const float*)d_in[7];
    const float* ln_ent_b = (const float*)d_in[8];
    const float* ln_rel_g = (const float*)d_in[9];
    const float* ln_rel_b = (const float*)d_in[10];
    const float* ln_ff_g  = (const float*)d_in[11];
    const float* ln_ff_b  = (const float*)d_in[12];
    const float* W1       = (const float*)d_in[13];
    const float* b1       = (const float*)d_in[14];
    const float* W2       = (const float*)d_in[15];
    const float* b2       = (const float*)d_in[16];
    const int*   src      = (const int*)d_in[17];
    const int*   dst      = (const int*)d_in[18];
    const int*   rid      = (const int*)d_in[19];
    float* out = (float*)d_out;

    // ---- workspace carve (bytes, 256-aligned) ----
    char* base = (char*)d_ws;
    auto carve = [&](size_t bytes) { char* p = base; base += (bytes + 255) & ~(size_t)255; return p; };
    unsigned short* xb    = (unsigned short*)carve((size_t)N_NODES * FDIM * 2);
    unsigned short* projb = (unsigned short*)carve((size_t)N_NODES * 768 * 2);
    unsigned short* rlnb  = (unsigned short*)carve((size_t)N_REL * FDIM * 2);
    unsigned short* frelb = (unsigned short*)carve((size_t)N_REL * FDIM * 2);
    unsigned short* WtP   = (unsigned short*)carve((size_t)768 * FDIM * 2);
    unsigned short* WtR   = (unsigned short*)carve((size_t)FDIM * FDIM * 2);
    unsigned short* W1t   = (unsigned short*)carve((size_t)1024 * FDIM * 2);
    unsigned short* W2t   = (unsigned short*)carve((size_t)FDIM * 1024 * 2);
    unsigned short* F0H   = (unsigned short*)carve((size_t)N_NODES * FDIM * 2);  // head-major fen
    unsigned short* hbH0  = (unsigned short*)carve((size_t)N_NODES * FDIM * 2);  // head-major hops
    unsigned short* hbH1  = (unsigned short*)carve((size_t)N_NODES * FDIM * 2);
    unsigned short* yb    = (unsigned short*)carve((size_t)N_NODES * FDIM * 2);
    unsigned short* t1b   = (unsigned short*)carve((size_t)N_NODES * 1024 * 2);
    float* rst     = (float*)carve((size_t)N_NODES * FDIM * 4);
    float* aH      = (float*)carve((size_t)N_EDGES * NHEAD * 4);   // head-major weights
    int*   csr_src = (int*)carve((size_t)(N_EDGES + 64) * 4);
    int*   csr_rid = (int*)carve((size_t)(N_EDGES + 64) * 4);
    int*   deg     = (int*)carve((size_t)N_NODES * 4);
    float* logdeg  = (float*)carve((size_t)N_NODES * 4);
    int*   offsets = (int*)carve((size_t)(N_NODES + 1) * 4);
    int*   cursor  = (int*)carve((size_t)N_NODES * 4);
    int*   bsum    = (int*)carve((size_t)SCAN_BLOCKS * 4);

    hipMemsetAsync(deg, 0, (size_t)N_NODES * 4, stream);

    // LN -> bf16
    ln_bf16_kernel<<<N_NODES, 64, 0, stream>>>(ent_feat, ln_ent_g, ln_ent_b, xb, N_NODES);
    ln_bf16_kernel<<<N_REL, 64, 0, stream>>>(rel_feat, ln_rel_g, ln_rel_b, rlnb, N_REL);

    // weight transposes (fp32 [K,N] -> bf16 [N,K]); WtP rows = [head | tail | ent]
    transpose_bf16_kernel<<<(65536 + 255) / 256, 256, 0, stream>>>(W_head, WtP,              FDIM, FDIM);
    transpose_bf16_kernel<<<(65536 + 255) / 256, 256, 0, stream>>>(W_tail, WtP + 256 * FDIM, FDIM, FDIM);
    transpose_bf16_kernel<<<(65536 + 255) / 256, 256, 0, stream>>>(W_ent,  WtP + 512 * FDIM, FDIM, FDIM);
    transpose_bf16_kernel<<<(65536 + 255) / 256, 256, 0, stream>>>(W_rel,  WtR, FDIM, FDIM);
    transpose_bf16_kernel<<<(262144 + 255) / 256, 256, 0, stream>>>(W1, W1t, FDIM, 1024);
    transpose_bf16_kernel<<<(262144 + 255) / 256, 256, 0, stream>>>(W2, W2t, 1024, FDIM);

    // fused projection GEMM: proj[N,768] = xb @ [Wh|Wt|We]  (bf16 out)
    dim3 gproj((N_NODES + 127) / 128, 768 / 128);
    mfma_gemm_bt<<<gproj, 256, 0, stream>>>(xb, WtP, nullptr, nullptr, nullptr, projb,
                                            N_NODES, FDIM, 768, 0);
    dim3 grel(1, FDIM / 128);
    mfma_gemm_bt<<<grel, 256, 0, stream>>>(rlnb, WtR, nullptr, nullptr, nullptr, frelb,
                                           N_REL, FDIM, FDIM, 0);

    // repack fen -> head-major F0H
    repack_fen_kernel<<<(N_NODES * 128 + 255) / 256, 256, 0, stream>>>(projb, F0H, N_NODES);

    // CSR build (count -> 3-phase parallel scan -> scatter)
    count_kernel<<<(N_EDGES + 255) / 256, 256, 0, stream>>>(dst, deg, N_EDGES);
    scan1_kernel<<<SCAN_BLOCKS, 256, 0, stream>>>(deg, offsets, bsum, N_NODES);
    scan2_kernel<<<1, 128, 0, stream>>>(bsum, SCAN_BLOCKS);
    scan3_kernel<<<SCAN_BLOCKS, 256, 0, stream>>>(deg, offsets, bsum, cursor, logdeg,
                                                  N_NODES, N_EDGES);
    scatter_kernel<<<(N_EDGES + 255) / 256, 256, 0, stream>>>(dst, src, rid, cursor,
                                                              csr_src, csr_rid, N_EDGES);

    // attention + fused softmax (normalized weights, head-major)
    edge_score_csr_kernel<<<(N_NODES + 3) / 4, 256, 0, stream>>>(
        projb, frelb, attn, csr_src, csr_rid, offsets, logdeg, aH, N_NODES);

    // 5-hop PPR diffusion, head-major with XCD affinity:
    // F0H -> hbH0 -> hbH1 -> hbH0 -> hbH1 -> hbH0
    int gdif = ((N_NODES + 3) / 4) * 8;
    diffuse_h_kernel<<<gdif, 256, 0, stream>>>(F0H,  F0H, aH, csr_src, offsets, hbH0, N_NODES);
    diffuse_h_kernel<<<gdif, 256, 0, stream>>>(hbH0, F0H, aH, csr_src, offsets, hbH1, N_NODES);
    diffuse_h_kernel<<<gdif, 256, 0, stream>>>(hbH1, F0H, aH, csr_src, offsets, hbH0, N_NODES);
    diffuse_h_kernel<<<gdif, 256, 0, stream>>>(hbH0, F0H, aH, csr_src, offsets, hbH1, N_NODES);
    diffuse_h_kernel<<<gdif, 256, 0, stream>>>(hbH1, F0H, aH, csr_src, offsets, hbH0, N_NODES);

    // residual + pre-LN (reads head-major hbH0)
    rst_ln_kernel<<<N_NODES, 64, 0, stream>>>(hbH0, ent_feat, ln_ff_g, ln_ff_b, rst, yb);

    // FFN1: t1 = relu(y@W1 + b1) [bf16], 64x128 tiles (2504 blocks)
    dim3 gff1((N_NODES + 63) / 64, 1024 / 128);
    mfma_gemm64_bt<<<gff1, 256, 0, stream>>>(yb, W1t, b1, nullptr, nullptr, t1b,
                                             N_NODES, FDIM, 1024, 1);
    // FFN2: out = t1@W2 + b2 + rst, 64x128 tiles
    dim3 gff2((N_NODES + 63) / 64, FDIM / 128);
    mfma_gemm64_bt<<<gff2, 256, 0, stream>>>(t1b, W2t, b2, rst, out, nullptr,
                                             N_NODES, 1024, FDIM, 0);
}

// Round 12
// 557.668 us; speedup vs baseline: 1.2513x; 1.1851x over previous
//
#include <hip/hip_runtime.h>

#define N_NODES 20000
#define N_EDGES 320000
#define N_REL   100
#define FDIM    256
#define NHEAD   8
#define HDIM    32
#define SCAN_BLOCKS ((N_NODES + 255) / 256)   // 79

using short8 = __attribute__((ext_vector_type(8))) short;   // 8 bf16 in 4 VGPRs
using f32x4  = __attribute__((ext_vector_type(4))) float;

__device__ inline unsigned short f2bf(float f) {
    union { float f; unsigned int u; } v; v.f = f;
    unsigned int r = v.u + 0x7fff + ((v.u >> 16) & 1);   // RNE
    return (unsigned short)(r >> 16);
}
__device__ inline float bf2f(unsigned short u) {
    union { unsigned int i; float f; } v; v.i = ((unsigned int)u) << 16; return v.f;
}
__device__ inline float4 bf4(ushort4 u) {
    return make_float4(bf2f(u.x), bf2f(u.y), bf2f(u.z), bf2f(u.w));
}
// unpack 8 bf16 (uint4) -> 8 fp32
__device__ inline void unpack8(float* d, uint4 u) {
    union { unsigned int u; float f; } t;
    t.u = u.x << 16;         d[0] = t.f;
    t.u = u.x & 0xffff0000u; d[1] = t.f;
    t.u = u.y << 16;         d[2] = t.f;
    t.u = u.y & 0xffff0000u; d[3] = t.f;
    t.u = u.z << 16;         d[4] = t.f;
    t.u = u.z & 0xffff0000u; d[5] = t.f;
    t.u = u.w << 16;         d[6] = t.f;
    t.u = u.w & 0xffff0000u; d[7] = t.f;
}
// acc[k] += w * bf16(u)[k], 8 elements
__device__ inline void fma8(float* acc, uint4 u, float w) {
    union { unsigned int u; float f; } t;
    t.u = u.x << 16;         acc[0] += w * t.f;
    t.u = u.x & 0xffff0000u; acc[1] += w * t.f;
    t.u = u.y << 16;         acc[2] += w * t.f;
    t.u = u.y & 0xffff0000u; acc[3] += w * t.f;
    t.u = u.z << 16;         acc[4] += w * t.f;
    t.u = u.z & 0xffff0000u; acc[5] += w * t.f;
    t.u = u.w << 16;         acc[6] += w * t.f;
    t.u = u.w & 0xffff0000u; acc[7] += w * t.f;
}

// ---------------------------------------------------------------------------
// LayerNorm over 256 features -> bf16 output. One wave per row.
// ---------------------------------------------------------------------------
__global__ __launch_bounds__(64) void ln_bf16_kernel(
    const float* __restrict__ in, const float* __restrict__ g,
    const float* __restrict__ b, unsigned short* __restrict__ out, int rows)
{
    int row = blockIdx.x;
    if (row >= rows) return;
    int tid = threadIdx.x;
    const float4 v = *(const float4*)(in + (size_t)row * FDIM + tid * 4);
    float s = v.x + v.y + v.z + v.w;
    float q = v.x * v.x + v.y * v.y + v.z * v.z + v.w * v.w;
    #pragma unroll
    for (int d = 1; d < 64; d <<= 1) { s += __shfl_xor(s, d); q += __shfl_xor(q, d); }
    float mean = s * (1.0f / FDIM);
    float var  = q * (1.0f / FDIM) - mean * mean;
    float inv  = rsqrtf(var + 1e-5f);
    float4 gg = *(const float4*)(g + tid * 4);
    float4 bb = *(const float4*)(b + tid * 4);
    ushort4 o;
    o.x = f2bf((v.x - mean) * inv * gg.x + bb.x);
    o.y = f2bf((v.y - mean) * inv * gg.y + bb.y);
    o.z = f2bf((v.z - mean) * inv * gg.z + bb.z);
    o.w = f2bf((v.w - mean) * inv * gg.w + bb.w);
    *(ushort4*)(out + (size_t)row * FDIM + tid * 4) = o;
}

// rst = bf2f(featH) + ent (fp32) ; y = LN(rst) (bf16). featH head-major [8][N][32].
__global__ __launch_bounds__(64) void rst_ln_kernel(
    const unsigned short* __restrict__ featH, const float* __restrict__ ent,
    const float* __restrict__ g, const float* __restrict__ b,
    float* __restrict__ rst, unsigned short* __restrict__ y)
{
    int row = blockIdx.x;
    int tid = threadIdx.x;
    int h = tid >> 3;                      // head of dims tid*4..tid*4+3
    const ushort4 fu = *(const ushort4*)(featH + ((size_t)h * N_NODES + row) * 32 + (tid & 7) * 4);
    const float4 f = bf4(fu);
    const float4 e = *(const float4*)(ent + (size_t)row * FDIM + tid * 4);
    float4 r;
    r.x = f.x + e.x; r.y = f.y + e.y; r.z = f.z + e.z; r.w = f.w + e.w;
    *(float4*)(rst + (size_t)row * FDIM + tid * 4) = r;
    float s = r.x + r.y + r.z + r.w;
    float q = r.x * r.x + r.y * r.y + r.z * r.z + r.w * r.w;
    #pragma unroll
    for (int d = 1; d < 64; d <<= 1) { s += __shfl_xor(s, d); q += __shfl_xor(q, d); }
    float mean = s * (1.0f / FDIM);
    float var  = q * (1.0f / FDIM) - mean * mean;
    float inv  = rsqrtf(var + 1e-5f);
    float4 gg = *(const float4*)(g + tid * 4);
    float4 bb = *(const float4*)(b + tid * 4);
    ushort4 o;
    o.x = f2bf((r.x - mean) * inv * gg.x + bb.x);
    o.y = f2bf((r.y - mean) * inv * gg.y + bb.y);
    o.z = f2bf((r.z - mean) * inv * gg.z + bb.z);
    o.w = f2bf((r.w - mean) * inv * gg.w + bb.w);
    *(ushort4*)(y + (size_t)row * FDIM + tid * 4) = o;
}

// Wt[n*K + k] = bf16(W[k*N + n])
__global__ void transpose_bf16_kernel(const float* __restrict__ W,
                                      unsigned short* __restrict__ Wt, int K, int N)
{
    int idx = blockIdx.x * 256 + threadIdx.x;
    if (idx >= K * N) return;
    int n = idx / K, k = idx - n * K;
    Wt[idx] = f2bf(W[(size_t)k * N + n]);
}

// repack fen (projb cols 512..767) -> F0 head-major [8][N][32], dword granularity
__global__ void repack_fen_kernel(const unsigned short* __restrict__ projb,
                                  unsigned short* __restrict__ F0, int n)
{
    int idx = blockIdx.x * 256 + threadIdx.x;
    int total = n * 128;                 // dwords
    if (idx >= total) return;
    int row = idx >> 7, d2 = idx & 127;
    int h = d2 >> 4, w = d2 & 15;
    ((unsigned int*)F0)[((size_t)h * n + row) * 16 + w] =
        ((const unsigned int*)projb)[(size_t)row * 384 + 256 + d2];
}

// ---------------------------------------------------------------------------
// bf16 MFMA GEMM (B^T): 128x128 tile, 4 waves, 4x4 frags, BK=32.
// ---------------------------------------------------------------------------
__global__ __launch_bounds__(256) void mfma_gemm_bt(
    const unsigned short* __restrict__ A, const unsigned short* __restrict__ Bt,
    const float* __restrict__ bias, const float* __restrict__ add,
    float* __restrict__ Cf, unsigned short* __restrict__ Cb,
    int M, int K, int N, int relu)
{
    __shared__ unsigned short As[128 * 32];
    __shared__ unsigned short Bs[128 * 32];
    int tid  = threadIdx.x;
    int wave = tid >> 6, lane = tid & 63;
    int quad = lane >> 4, l16 = lane & 15;
    int m0 = blockIdx.x * 128, n0 = blockIdx.y * 128;
    int wr = (wave >> 1) * 64, wc = (wave & 1) * 64;

    f32x4 acc[4][4] = {};

    int cA = tid, cB = tid + 256;
    int rA0 = cA >> 2, kA0 = (cA & 3) * 8;
    int rB0 = cB >> 2, kB0 = (cB & 3) * 8;
    int rA = m0 + rA0; if (rA >= M) rA = M - 1;
    int rB = m0 + rB0; if (rB >= M) rB = M - 1;
    const unsigned short* gA0 = A + (size_t)rA * K + kA0;
    const unsigned short* gA1 = A + (size_t)rB * K + kB0;
    const unsigned short* gB0 = Bt + (size_t)(n0 + rA0) * K + kA0;
    const unsigned short* gB1 = Bt + (size_t)(n0 + rB0) * K + kB0;

    for (int k0 = 0; k0 < K; k0 += 32) {
        ((uint4*)As)[cA] = *(const uint4*)(gA0 + k0);
        ((uint4*)As)[cB] = *(const uint4*)(gA1 + k0);
        ((uint4*)Bs)[cA] = *(const uint4*)(gB0 + k0);
        ((uint4*)Bs)[cB] = *(const uint4*)(gB1 + k0);
        __syncthreads();
        short8 af[4], bfr[4];
        #pragma unroll
        for (int i = 0; i < 4; ++i)
            af[i] = *(const short8*)(As + (wr + i * 16 + l16) * 32 + quad * 8);
        #pragma unroll
        for (int j = 0; j < 4; ++j)
            bfr[j] = *(const short8*)(Bs + (wc + j * 16 + l16) * 32 + quad * 8);
        #pragma unroll
        for (int i = 0; i < 4; ++i)
            #pragma unroll
            for (int j = 0; j < 4; ++j)
                acc[i][j] = __builtin_amdgcn_mfma_f32_16x16x32_bf16(
                    af[i], bfr[j], acc[i][j], 0, 0, 0);
        __syncthreads();
    }

    #pragma unroll
    for (int i = 0; i < 4; ++i) {
        #pragma unroll
        for (int j = 0; j < 4; ++j) {
            int col = n0 + wc + j * 16 + l16;
            float bsv = bias ? bias[col] : 0.0f;
            #pragma unroll
            for (int r = 0; r < 4; ++r) {
                int row = m0 + wr + i * 16 + quad * 4 + r;
                if (row < M) {
                    float v = acc[i][j][r] + bsv;
                    if (relu) v = fmaxf(v, 0.0f);
                    if (add)  v += add[(size_t)row * N + col];
                    if (Cf) Cf[(size_t)row * N + col] = v;
                    else    Cb[(size_t)row * N + col] = f2bf(v);
                }
            }
        }
    }
}

// ---------------------------------------------------------------------------
// 64x128-tile variant (FFN2): 4 waves, 4x2 frags, LDS 12 KB.
// ---------------------------------------------------------------------------
__global__ __launch_bounds__(256) void mfma_gemm64_bt(
    const unsigned short* __restrict__ A, const unsigned short* __restrict__ Bt,
    const float* __restrict__ bias, const float* __restrict__ add,
    float* __restrict__ Cf, int M, int K, int N)
{
    __shared__ unsigned short As[64 * 32];
    __shared__ unsigned short Bs[128 * 32];
    int tid  = threadIdx.x;
    int wave = tid >> 6, lane = tid & 63;
    int quad = lane >> 4, l16 = lane & 15;
    int m0 = blockIdx.x * 64, n0 = blockIdx.y * 128;
    int wc = wave * 32;

    f32x4 acc[4][2] = {};

    int rA0 = tid >> 2, kA0 = (tid & 3) * 8;
    int cB0 = tid, cB1 = tid + 256;
    int rB0 = cB0 >> 2, kB0 = (cB0 & 3) * 8;
    int rB1 = cB1 >> 2, kB1 = (cB1 & 3) * 8;
    int rA = m0 + rA0; if (rA >= M) rA = M - 1;
    const unsigned short* gA  = A + (size_t)rA * K + kA0;
    const unsigned short* gB0 = Bt + (size_t)(n0 + rB0) * K + kB0;
    const unsigned short* gB1 = Bt + (size_t)(n0 + rB1) * K + kB1;

    for (int k0 = 0; k0 < K; k0 += 32) {
        ((uint4*)As)[tid] = *(const uint4*)(gA + k0);
        ((uint4*)Bs)[cB0] = *(const uint4*)(gB0 + k0);
        ((uint4*)Bs)[cB1] = *(const uint4*)(gB1 + k0);
        __syncthreads();
        short8 af[4], bfr[2];
        #pragma unroll
        for (int i = 0; i < 4; ++i)
            af[i] = *(const short8*)(As + (i * 16 + l16) * 32 + quad * 8);
        #pragma unroll
        for (int j = 0; j < 2; ++j)
            bfr[j] = *(const short8*)(Bs + (wc + j * 16 + l16) * 32 + quad * 8);
        #pragma unroll
        for (int i = 0; i < 4; ++i)
            #pragma unroll
            for (int j = 0; j < 2; ++j)
                acc[i][j] = __builtin_amdgcn_mfma_f32_16x16x32_bf16(
                    af[i], bfr[j], acc[i][j], 0, 0, 0);
        __syncthreads();
    }

    #pragma unroll
    for (int i = 0; i < 4; ++i) {
        #pragma unroll
        for (int j = 0; j < 2; ++j) {
            int col = n0 + wc + j * 16 + l16;
            float bsv = bias ? bias[col] : 0.0f;
            #pragma unroll
            for (int r = 0; r < 4; ++r) {
                int row = m0 + i * 16 + quad * 4 + r;
                if (row < M) {
                    float v = acc[i][j][r] + bsv;
                    if (add) v += add[(size_t)row * N + col];
                    Cf[(size_t)row * N + col] = v;
                }
            }
        }
    }
}

// ---------------------------------------------------------------------------
// Graph plumbing: degree count -> 3-phase parallel scan -> scatter
// ---------------------------------------------------------------------------
__global__ void count_kernel(const int* __restrict__ dst, int* __restrict__ deg, int E)
{
    int i = blockIdx.x * blockDim.x + threadIdx.x;
    if (i < E) atomicAdd(&deg[dst[i]], 1);
}

__global__ __launch_bounds__(256) void scan1_kernel(
    const int* __restrict__ deg, int* __restrict__ offsets, int* __restrict__ bsum, int n)
{
    __shared__ int tmp[256];
    int tid = threadIdx.x;
    int i = blockIdx.x * 256 + tid;
    int v = (i < n) ? deg[i] : 0;
    tmp[tid] = v;
    __syncthreads();
    for (int d = 1; d < 256; d <<= 1) {
        int u = (tid >= d) ? tmp[tid - d] : 0;
        __syncthreads();
        tmp[tid] += u;
        __syncthreads();
    }
    if (i < n) offsets[i] = tmp[tid] - v;
    if (tid == 255) bsum[blockIdx.x] = tmp[255];
}

__global__ __launch_bounds__(128) void scan2_kernel(int* __restrict__ bsum, int nb)
{
    __shared__ int tmp[128];
    int tid = threadIdx.x;
    int v = (tid < nb) ? bsum[tid] : 0;
    tmp[tid] = v;
    __syncthreads();
    for (int d = 1; d < 128; d <<= 1) {
        int u = (tid >= d) ? tmp[tid - d] : 0;
        __syncthreads();
        tmp[tid] += u;
        __syncthreads();
    }
    if (tid < nb) bsum[tid] = tmp[tid] - v;
}

__global__ __launch_bounds__(256) void scan3_kernel(
    const int* __restrict__ deg, int* __restrict__ offsets,
    const int* __restrict__ bsum, int* __restrict__ cursor,
    float* __restrict__ logdeg, int n, int E)
{
    int i = blockIdx.x * 256 + threadIdx.x;
    if (i < n) {
        int o = offsets[i] + bsum[blockIdx.x];
        offsets[i] = o;
        cursor[i]  = o;
        logdeg[i]  = logf((float)deg[i]);
    }
    if (i == 0) offsets[n] = E;
}

__global__ void scatter_kernel(const int* __restrict__ dst, const int* __restrict__ src,
                               const int* __restrict__ rid, int* __restrict__ cursor,
                               int* __restrict__ csr_src, int* __restrict__ csr_rid, int E)
{
    int i = blockIdx.x * blockDim.x + threadIdx.x;
    if (i < E) {
        int p = atomicAdd(&cursor[dst[i]], 1);
        csr_src[p] = src[i];
        csr_rid[p] = rid[i];
    }
}

// ---------------------------------------------------------------------------
// CSR edge attention + fused softmax. One wave per dst node (4/block).
// 16 lanes per edge, 8 edges in flight. Writes normalized weights HEAD-MAJOR
// aH[h][e].
// ---------------------------------------------------------------------------
__global__ __launch_bounds__(256) void edge_score_csr_kernel(
    const unsigned short* __restrict__ proj,   // [N,768]: fh | ftl | fen
    const unsigned short* __restrict__ frel,   // [R,256] bf16
    const float* __restrict__ attn,
    const int* __restrict__ csr_src, const int* __restrict__ csr_rid,
    const int* __restrict__ offsets, const float* __restrict__ logdeg,
    float* __restrict__ aH, int n)
{
    int node = blockIdx.x * 4 + (threadIdx.x >> 6);
    if (node >= n) return;
    int tid = threadIdx.x & 63;
    int g = tid >> 4, li = tid & 15;
    int start = offsets[node], end = offsets[node + 1];
    float scale = logdeg[node] * (1.0f / 32.0f);

    float tv[16], at[16];
    {
        const unsigned short* tp = proj + (size_t)node * 768 + 256 + li * 16;
        uint4 a0 = *(const uint4*)tp, a1 = *(const uint4*)(tp + 8);
        unpack8(tv, a0); unpack8(tv + 8, a1);
        const float4* ap = (const float4*)(attn + li * 16);
        float4 f;
        f = ap[0]; at[0] = f.x; at[1] = f.y; at[2]  = f.z; at[3]  = f.w;
        f = ap[1]; at[4] = f.x; at[5] = f.y; at[6]  = f.z; at[7]  = f.w;
        f = ap[2]; at[8] = f.x; at[9] = f.y; at[10] = f.z; at[11] = f.w;
        f = ap[3]; at[12] = f.x; at[13] = f.y; at[14] = f.z; at[15] = f.w;
    }

    float denom = 0.f;
    for (int p = start; p < end; p += 8) {
        int  pe[2]; bool va[2]; uint4 h0[2], h1[2], r0[2], r1[2];
        #pragma unroll
        for (int t = 0; t < 2; ++t) {
            pe[t] = p + t * 4 + g;
            va[t] = pe[t] < end;
            int q = va[t] ? pe[t] : end - 1;
            int s = csr_src[q], r = csr_rid[q];
            const unsigned short* hp = proj + (size_t)s * 768 + li * 16;
            const unsigned short* rp = frel + (size_t)r * FDIM + li * 16;
            h0[t] = *(const uint4*)hp; h1[t] = *(const uint4*)(hp + 8);
            r0[t] = *(const uint4*)rp; r1[t] = *(const uint4*)(rp + 8);
        }
        #pragma unroll
        for (int t = 0; t < 2; ++t) {
            float hv[16], rv[16];
            unpack8(hv, h0[t]); unpack8(hv + 8, h1[t]);
            unpack8(rv, r0[t]); unpack8(rv + 8, r1[t]);
            float sum = 0.f;
            #pragma unroll
            for (int k = 0; k < 16; ++k) {
                float m = hv[k] * tv[k] * rv[k];
                m = (m > 0.f) ? m : 0.2f * m;
                sum += m * at[k];
            }
            sum += __shfl_xor(sum, 1);
            float ex = expf(sum * scale);
            if (va[t] && ((li & 1) == 0)) {
                aH[(size_t)(li >> 1) * N_EDGES + pe[t]] = ex;
                denom += ex;
            }
        }
    }
    denom += __shfl_xor(denom, 16);
    denom += __shfl_xor(denom, 32);
    #pragma unroll
    for (int h2 = 0; h2 < 8; ++h2) {
        float inv = 1.0f / __shfl(denom, 2 * h2);
        for (int e = start + tid; e < end; e += 64)
            aH[(size_t)h2 * N_EDGES + e] *= inv;
    }
}

// ---------------------------------------------------------------------------
// One PPR hop, head-major F[h][n][32] bf16, head = blockIdx % 8 (XCD affinity).
// Wave = 2 nodes x 1 head; per node a 32-lane half-wave: 8 edge slots x
// 4 uint4-lanes (16 B/lane). Fast path unrolls 2 windows -> 16 edges
// (32 x 64B slices) in flight per wave. 80k waves total.
// ---------------------------------------------------------------------------
__global__ __launch_bounds__(256) void diffuse_h_kernel(
    const unsigned short* __restrict__ fin,    // [8][n][32]
    const unsigned short* __restrict__ feat0,  // [8][n][32]
    const float* __restrict__ aH,              // [8][E]
    const int* __restrict__ csr_src, const int* __restrict__ offsets,
    unsigned short* __restrict__ fout, int n)
{
    int h = blockIdx.x & 7;
    int node = (blockIdx.x >> 3) * 8 + (threadIdx.x >> 5);   // 8 nodes per block
    if (node >= n) return;
    int t32 = threadIdx.x & 31;
    int g = t32 >> 2, li = t32 & 3;        // g: edge slot 0..7, li: uint4 in 64B slice
    int start = offsets[node], end = offsets[node + 1];
    const uint4* finh = (const uint4*)fin + (size_t)h * n * 4;
    const float* ah = aH + (size_t)h * N_EDGES;
    float acc[8] = {};

    int p = start;
    for (; p + 16 <= end; p += 16) {       // 2 full windows, no clamps: 16 edges in flight
        int q0 = p + g, q1 = p + 8 + g;
        int s0 = csr_src[q0], s1 = csr_src[q1];
        float w0 = ah[q0], w1 = ah[q1];
        uint4 u0 = finh[(size_t)s0 * 4 + li];
        uint4 u1 = finh[(size_t)s1 * 4 + li];
        fma8(acc, u0, w0);
        fma8(acc, u1, w1);
    }
    for (; p < end; p += 8) {              // tail window with clamps
        int pe = p + g;
        int q = (pe < end) ? pe : end - 1;
        int s = csr_src[q];
        float w = (pe < end) ? ah[q] : 0.0f;
        uint4 u = finh[(size_t)s * 4 + li];
        fma8(acc, u, w);
    }
    // reduce over the 8 edge slots (lane bits 2..4; stays within the half-wave)
    #pragma unroll
    for (int k = 0; k < 8; ++k) {
        acc[k] += __shfl_xor(acc[k], 4);
        acc[k] += __shfl_xor(acc[k], 8);
        acc[k] += __shfl_xor(acc[k], 16);
    }
    if (g == 0) {
        uint4 f0u = ((const uint4*)feat0)[((size_t)h * n + node) * 4 + li];
        float f0[8];
        unpack8(f0, f0u);
        unsigned short o[8];
        #pragma unroll
        for (int k = 0; k < 8; ++k) o[k] = f2bf(0.9f * acc[k] + 0.1f * f0[k]);
        ((uint4*)fout)[((size_t)h * n + node) * 4 + li] = *(uint4*)o;
    }
}

// ---------------------------------------------------------------------------
extern "C" void kernel_launch(void* const* d_in, const int* in_sizes, int n_in,
                              void* d_out, int out_size, void* d_ws, size_t ws_size,
                              hipStream_t stream)
{
    const float* ent_feat = (const float*)d_in[0];
    const float* rel_feat = (const float*)d_in[1];
    const float* W_head   = (const float*)d_in[2];
    const float* W_tail   = (const float*)d_in[3];
    const float* W_ent    = (const float*)d_in[4];
    const float* W_rel    = (const float*)d_in[5];
    const float* attn     = (const float*)d_in[6];
    const float* ln_ent_g = (const float*)d_in[7];
    const float* ln_ent_b = (const float*)d_in[8];
    const float* ln_rel_g = (const float*)d_in[9];
    const float* ln_rel_b = (const float*)d_in[10];
    const float* ln_ff_g  = (const float*)d_in[11];
    const float* ln_ff_b  = (const float*)d_in[12];
    const float* W1       = (const float*)d_in[13];
    const float* b1       = (const float*)d_in[14];
    const float* W2       = (const float*)d_in[15];
    const float* b2       = (const float*)d_in[16];
    const int*   src      = (const int*)d_in[17];
    const int*   dst      = (const int*)d_in[18];
    const int*   rid      = (const int*)d_in[19];
    float* out = (float*)d_out;

    // ---- workspace carve (bytes, 256-aligned) ----
    char* base = (char*)d_ws;
    auto carve = [&](size_t bytes) { char* p = base; base += (bytes + 255) & ~(size_t)255; return p; };
    unsigned short* xb    = (unsigned short*)carve((size_t)N_NODES * FDIM * 2);
    unsigned short* projb = (unsigned short*)carve((size_t)N_NODES * 768 * 2);
    unsigned short* rlnb  = (unsigned short*)carve((size_t)N_REL * FDIM * 2);
    unsigned short* frelb = (unsigned short*)carve((size_t)N_REL * FDIM * 2);
    unsigned short* WtP   = (unsigned short*)carve((size_t)768 * FDIM * 2);
    unsigned short* WtR   = (unsigned short*)carve((size_t)FDIM * FDIM * 2);
    unsigned short* W1t   = (unsigned short*)carve((size_t)1024 * FDIM * 2);
    unsigned short* W2t   = (unsigned short*)carve((size_t)FDIM * 1024 * 2);
    unsigned short* F0H   = (unsigned short*)carve((size_t)N_NODES * FDIM * 2);  // head-major fen
    unsigned short* hbH0  = (unsigned short*)carve((size_t)N_NODES * FDIM * 2);  // head-major hops
    unsigned short* hbH1  = (unsigned short*)carve((size_t)N_NODES * FDIM * 2);
    unsigned short* yb    = (unsigned short*)carve((size_t)N_NODES * FDIM * 2);
    unsigned short* t1b   = (unsigned short*)carve((size_t)N_NODES * 1024 * 2);
    float* rst     = (float*)carve((size_t)N_NODES * FDIM * 4);
    float* aH      = (float*)carve((size_t)N_EDGES * NHEAD * 4);   // head-major weights
    int*   csr_src = (int*)carve((size_t)(N_EDGES + 64) * 4);
    int*   csr_rid = (int*)carve((size_t)(N_EDGES + 64) * 4);
    int*   deg     = (int*)carve((size_t)N_NODES * 4);
    float* logdeg  = (float*)carve((size_t)N_NODES * 4);
    int*   offsets = (int*)carve((size_t)(N_NODES + 1) * 4);
    int*   cursor  = (int*)carve((size_t)N_NODES * 4);
    int*   bsum    = (int*)carve((size_t)SCAN_BLOCKS * 4);

    hipMemsetAsync(deg, 0, (size_t)N_NODES * 4, stream);

    // LN -> bf16
    ln_bf16_kernel<<<N_NODES, 64, 0, stream>>>(ent_feat, ln_ent_g, ln_ent_b, xb, N_NODES);
    ln_bf16_kernel<<<N_REL, 64, 0, stream>>>(rel_feat, ln_rel_g, ln_rel_b, rlnb, N_REL);

    // weight transposes (fp32 [K,N] -> bf16 [N,K]); WtP rows = [head | tail | ent]
    transpose_bf16_kernel<<<(65536 + 255) / 256, 256, 0, stream>>>(W_head, WtP,              FDIM, FDIM);
    transpose_bf16_kernel<<<(65536 + 255) / 256, 256, 0, stream>>>(W_tail, WtP + 256 * FDIM, FDIM, FDIM);
    transpose_bf16_kernel<<<(65536 + 255) / 256, 256, 0, stream>>>(W_ent,  WtP + 512 * FDIM, FDIM, FDIM);
    transpose_bf16_kernel<<<(65536 + 255) / 256, 256, 0, stream>>>(W_rel,  WtR, FDIM, FDIM);
    transpose_bf16_kernel<<<(262144 + 255) / 256, 256, 0, stream>>>(W1, W1t, FDIM, 1024);
    transpose_bf16_kernel<<<(262144 + 255) / 256, 256, 0, stream>>>(W2, W2t, 1024, FDIM);

    // fused projection GEMM: proj[N,768] = xb @ [Wh|Wt|We]  (bf16 out)
    dim3 gproj((N_NODES + 127) / 128, 768 / 128);
    mfma_gemm_bt<<<gproj, 256, 0, stream>>>(xb, WtP, nullptr, nullptr, nullptr, projb,
                                            N_NODES, FDIM, 768, 0);
    dim3 grel(1, FDIM / 128);
    mfma_gemm_bt<<<grel, 256, 0, stream>>>(rlnb, WtR, nullptr, nullptr, nullptr, frelb,
                                           N_REL, FDIM, FDIM, 0);

    // repack fen -> head-major F0H
    repack_fen_kernel<<<(N_NODES * 128 + 255) / 256, 256, 0, stream>>>(projb, F0H, N_NODES);

    // CSR build (count -> 3-phase parallel scan -> scatter)
    count_kernel<<<(N_EDGES + 255) / 256, 256, 0, stream>>>(dst, deg, N_EDGES);
    scan1_kernel<<<SCAN_BLOCKS, 256, 0, stream>>>(deg, offsets, bsum, N_NODES);
    scan2_kernel<<<1, 128, 0, stream>>>(bsum, SCAN_BLOCKS);
    scan3_kernel<<<SCAN_BLOCKS, 256, 0, stream>>>(deg, offsets, bsum, cursor, logdeg,
                                                  N_NODES, N_EDGES);
    scatter_kernel<<<(N_EDGES + 255) / 256, 256, 0, stream>>>(dst, src, rid, cursor,
                                                              csr_src, csr_rid, N_EDGES);

    // attention + fused softmax (normalized weights, head-major)
    edge_score_csr_kernel<<<(N_NODES + 3) / 4, 256, 0, stream>>>(
        projb, frelb, attn, csr_src, csr_rid, offsets, logdeg, aH, N_NODES);

    // 5-hop PPR diffusion, head-major with XCD affinity:
    // F0H -> hbH0 -> hbH1 -> hbH0 -> hbH1 -> hbH0
    int gdif = ((N_NODES + 7) / 8) * 8;
    diffuse_h_kernel<<<gdif, 256, 0, stream>>>(F0H,  F0H, aH, csr_src, offsets, hbH0, N_NODES);
    diffuse_h_kernel<<<gdif, 256, 0, stream>>>(hbH0, F0H, aH, csr_src, offsets, hbH1, N_NODES);
    diffuse_h_kernel<<<gdif, 256, 0, stream>>>(hbH1, F0H, aH, csr_src, offsets, hbH0, N_NODES);
    diffuse_h_kernel<<<gdif, 256, 0, stream>>>(hbH0, F0H, aH, csr_src, offsets, hbH1, N_NODES);
    diffuse_h_kernel<<<gdif, 256, 0, stream>>>(hbH1, F0H, aH, csr_src, offsets, hbH0, N_NODES);

    // residual + pre-LN (reads head-major hbH0)
    rst_ln_kernel<<<N_NODES, 64, 0, stream>>>(hbH0, ent_feat, ln_ff_g, ln_ff_b, rst, yb);

    // FFN1: t1 = relu(y@W1 + b1) [bf16], 128x128 tiles (measured-good config)
    dim3 gff1((N_NODES + 127) / 128, 1024 / 128);
    mfma_gemm_bt<<<gff1, 256, 0, stream>>>(yb, W1t, b1, nullptr, nullptr, t1b,
                                           N_NODES, FDIM, 1024, 1);
    // FFN2: out = t1@W2 + b2 + rst, 64x128 tiles
    dim3 gff2((N_NODES + 63) / 64, FDIM / 128);
    mfma_gemm64_bt<<<gff2, 256, 0, stream>>>(t1b, W2t, b2, rst, out,
                                             N_NODES, 1024, FDIM);
}